// Round 12
// baseline (52.278 us; speedup 1.0000x reference)
//
#include <hip/hip_runtime.h>

#define BATCH 4096
#define CTX 10
#define NEG 20
#define DIM 128
#define V 50000
#define NPOS (BATCH * CTX)            // 40960
#define NNEG (BATCH * CTX * NEG)      // 819200
#define WSTRIP 512                    // negative occurrences per wave-task
#define NWSTRIP (NNEG / WSTRIP)       // 1600
#define NWTASK (NWSTRIP * 8)          // 12800 wave partials
#define WPB 4
#define NNEGBLK (NWTASK / WPB)        // 3200 blocks
#define NPOSBLK (NPOS / 64)           // 640 blocks
#define NPART (NWTASK + NPOSBLK)      // 13440
#define IVSTR 136                     // LDS ivec row stride in halves (272B)

// ---- workspace layout (bytes); ws_size ~268MB (observed R10) ----
#define WS_EMBO 0
#define WS_EMBO_SZ ((size_t)V * DIM * 2)              // 12.8 MB f16
#define WS_IVEC (WS_EMBO + WS_EMBO_SZ)
#define WS_IVEC_SZ ((size_t)BATCH * DIM * 2)          // 1 MB f16
#define WS_PART (WS_IVEC + WS_IVEC_SZ)
#define WS_NEED (WS_PART + (size_t)NPART * 4)

typedef _Float16 half2v __attribute__((ext_vector_type(2)));
// EXACTLY 16 bytes: one uint4 <-> 4 half2 <-> 8 f16  (R11 bug: was 32B, read garbage)
union U16 { uint4 u; half2v h[4]; _Float16 f[8]; };

__device__ __forceinline__ float log_sigmoid(float x) {
    return fminf(x, 0.0f) - __logf(1.0f + __expf(-fabsf(x)));
}

// dot of one 16B chunk each side (8 f16 pairs), f32 accumulate
__device__ __forceinline__ float dot16(const uint4& a, const uint4& b, float acc) {
    U16 ua, ub; ua.u = a; ub.u = b;
#if __has_builtin(__builtin_amdgcn_fdot2)
    #pragma unroll
    for (int j = 0; j < 4; ++j)
        acc = __builtin_amdgcn_fdot2(ua.h[j], ub.h[j], acc, false);
#else
    #pragma unroll
    for (int j = 0; j < 8; ++j)
        acc = fmaf((float)ua.f[j], (float)ub.f[j], acc);
#endif
    return acc;
}

// emb_o f32 -> f16 (streaming, 3125 blocks x 8 elems/thread)
__global__ __launch_bounds__(256) void conv_embo(
    const float* __restrict__ emb_o, _Float16* __restrict__ embo_h)
{
    const size_t gid = (size_t)blockIdx.x * 256 + threadIdx.x;
    const float4 a = reinterpret_cast<const float4*>(emb_o)[2 * gid];
    const float4 b = reinterpret_cast<const float4*>(emb_o)[2 * gid + 1];
    U16 o;
    o.f[0]=(_Float16)a.x; o.f[1]=(_Float16)a.y; o.f[2]=(_Float16)a.z; o.f[3]=(_Float16)a.w;
    o.f[4]=(_Float16)b.x; o.f[5]=(_Float16)b.y; o.f[6]=(_Float16)b.z; o.f[7]=(_Float16)b.w;
    reinterpret_cast<uint4*>(embo_h)[gid] = o.u;
}

// gather+convert the 4096 used ivecs -> dense f16 table (256 blocks)
__global__ __launch_bounds__(256) void conv_ivec(
    const float* __restrict__ emb_i, const int* __restrict__ iword,
    _Float16* __restrict__ ivec_h)
{
    const int gid = blockIdx.x * 256 + threadIdx.x;   // 16 threads per row
    const int row = gid >> 4, f = gid & 15;
    const int iw  = iword[row];
    const float4 a = reinterpret_cast<const float4*>(emb_i)[(size_t)iw * 32 + 2 * f];
    const float4 b = reinterpret_cast<const float4*>(emb_i)[(size_t)iw * 32 + 2 * f + 1];
    U16 o;
    o.f[0]=(_Float16)a.x; o.f[1]=(_Float16)a.y; o.f[2]=(_Float16)a.z; o.f[3]=(_Float16)a.w;
    o.f[4]=(_Float16)b.x; o.f[5]=(_Float16)b.y; o.f[6]=(_Float16)b.z; o.f[7]=(_Float16)b.w;
    reinterpret_cast<uint4*>(ivec_h)[(size_t)row * 16 + f] = o.u;
}

// Negatives, f16: wave-task = 512 consecutive nwords occ x slice (blockIdx&7
// -> one XCD, emb_o slice L2-resident, proven R8/R9). Barrier-free;
// wave-private LDS. Row = 256B = 4 lines/item: 8-lane group, 2x16B per lane.
__global__ __launch_bounds__(256) void sgns_neg(
    const _Float16* __restrict__ embo_h, const _Float16* __restrict__ ivec_h,
    const int* __restrict__ nwords, float* __restrict__ partials)
{
    __shared__ _Float16 s_ivec[WPB][4 * IVSTR];
    __shared__ int      wq[WPB][WSTRIP];

    const int tid   = threadIdx.x;
    const int wave  = tid >> 6;
    const int lane  = tid & 63;
    const int slice = blockIdx.x & 7;
    const int ws    = (blockIdx.x >> 3) * WPB + wave;
    const int wbase = ws * WSTRIP;
    const int b_lo  = wbase / 200;

    // stage this wave's <=4 ivec rows from the dense f16 table (64 chunks)
    _Float16* __restrict__ siv = s_ivec[wave];
    {
        const int r = lane >> 4, f = lane & 15;
        const int b = min(b_lo + r, BATCH - 1);
        const uint4 v = reinterpret_cast<const uint4*>(ivec_h)[(size_t)b * 16 + f];
        *reinterpret_cast<uint4*>(&siv[r * IVSTR + f * 8]) = v;
    }

    // ballot-compact 512 occurrences into the wave-private queue
    int* __restrict__ q = wq[wave];
    const unsigned long long lt = (1ull << lane) - 1;
    int qn = 0;
    #pragma unroll
    for (int h = 0; h < 8; ++h) {
        const int j  = wbase + h * 64 + lane;
        const int w  = nwords[j];
        const int bl = j / 200 - b_lo;            // 0..3
        const bool keep = ((w & 7) == slice);
        const unsigned long long m = __ballot(keep);
        if (keep) q[qn + __popcll(m & lt)] = (w << 2) | bl;
        qn += __popcll(m);
    }

    // 8 groups x 8 lanes; 2-deep pipeline; 2 x 16B row loads per lane
    const int g = lane >> 3, sub = lane & 7;
    float acc = 0.0f;
    uint4 c0 = {0,0,0,0}, c1 = {0,0,0,0}, n0 = {0,0,0,0}, n1 = {0,0,0,0};
    int i = g;
    if (i < qn) {
        const uint4* __restrict__ rp =
            reinterpret_cast<const uint4*>(embo_h + (size_t)(q[i] >> 2) * DIM);
        c0 = rp[sub]; c1 = rp[sub + 8];
    }
    for (; i < qn; i += 8) {
        const int pk = q[i];
        const int i2 = i + 8;
        if (i2 < qn) {
            const uint4* __restrict__ rp =
                reinterpret_cast<const uint4*>(embo_h + (size_t)(q[i2] >> 2) * DIM);
            n0 = rp[sub]; n1 = rp[sub + 8];
        }
        __builtin_amdgcn_sched_barrier(0);   // prefetch issues before compute

        const _Float16* __restrict__ qp = &siv[(pk & 3) * IVSTR + sub * 8];
        const uint4 q0 = *reinterpret_cast<const uint4*>(qp);
        const uint4 q1 = *reinterpret_cast<const uint4*>(qp + 64);
        float pd = dot16(c0, q0, 0.0f);
        pd = dot16(c1, q1, pd);
        pd += __shfl_xor(pd, 1, 64);
        pd += __shfl_xor(pd, 2, 64);
        pd += __shfl_xor(pd, 4, 64);
        acc += log_sigmoid(-pd);             // counted 8x; scaled at write

        c0 = n0; c1 = n1;
    }

    #pragma unroll
    for (int off = 32; off > 0; off >>= 1)
        acc += __shfl_xor(acc, off, 64);
    if (lane == 0)
        partials[blockIdx.x * WPB + wave] = 0.125f * acc;
}

// Positives (4.7%), f16: 4-lane groups, 4 chunks per lane each side.
__global__ __launch_bounds__(256) void sgns_pos(
    const _Float16* __restrict__ embo_h, const _Float16* __restrict__ ivec_h,
    const int* __restrict__ owords, float* __restrict__ partials)
{
    __shared__ float s_wsum[4];
    const int tid  = threadIdx.x;
    const int item = (blockIdx.x * 256 + tid) >> 2;
    const int sub  = tid & 3;
    const int b    = item / 10;
    const int w    = owords[item];

    const uint4* __restrict__ rp = reinterpret_cast<const uint4*>(embo_h + (size_t)w * DIM);
    const uint4* __restrict__ qp = reinterpret_cast<const uint4*>(ivec_h + (size_t)b * DIM);
    float pd = 0.0f;
    #pragma unroll
    for (int u = 0; u < 4; ++u)
        pd = dot16(rp[sub + 4 * u], qp[sub + 4 * u], pd);
    pd += __shfl_xor(pd, 1, 64);
    pd += __shfl_xor(pd, 2, 64);
    float acc = log_sigmoid(pd);

    #pragma unroll
    for (int off = 32; off > 0; off >>= 1)
        acc += __shfl_xor(acc, off, 64);
    if ((tid & 63) == 0) s_wsum[tid >> 6] = acc;
    __syncthreads();
    if (tid == 0)
        partials[NWTASK + blockIdx.x] =
            0.25f * (s_wsum[0] + s_wsum[1] + s_wsum[2] + s_wsum[3]);
}

__global__ __launch_bounds__(256) void sgns_reduce(
    const float* __restrict__ partials, float* __restrict__ out)
{
    __shared__ float s[4];
    const int tid = threadIdx.x;
    float acc = 0.0f;
    for (int i = tid; i < NPART; i += 256) acc += partials[i];
    #pragma unroll
    for (int off = 32; off > 0; off >>= 1)
        acc += __shfl_xor(acc, off, 64);
    if ((tid & 63) == 0) s[tid >> 6] = acc;
    __syncthreads();
    if (tid == 0)
        out[0] = -(s[0] + s[1] + s[2] + s[3]) / (float)(BATCH * CTX);
}

// ---------------- fallback (R6-style, f32) if ws too small ----------------
#define NWORDS (CTX + CTX * NEG)
#define GPR 32
#define NPASS 7

__global__ __launch_bounds__(256) void sgns_partial_fb(
    const float* __restrict__ emb_i, const float* __restrict__ emb_o,
    const int* __restrict__ iword, const int* __restrict__ owords,
    const int* __restrict__ nwords, float* __restrict__ wsum)
{
    const int gtid = blockIdx.x * 256 + threadIdx.x;
    const int G = gtid >> 2, sub = gtid & 3;
    const int b = G >> 5, gl = G & 31;
    const int iw = iword[b];
    const float4* __restrict__ qp =
        reinterpret_cast<const float4*>(emb_i + (size_t)iw * DIM) + sub;
    float4 qv[8];
    #pragma unroll
    for (int u = 0; u < 8; ++u) qv[u] = qp[4 * u];
    int idx[NPASS];
    #pragma unroll
    for (int p = 0; p < NPASS; ++p) {
        const int j = gl + GPR * p;
        idx[p] = (j >= NWORDS) ? -1
               : (j < CTX)     ? owords[b * CTX + j]
                               : nwords[b * (CTX * NEG) + (j - CTX)];
    }
    float acc = 0.0f;
    #pragma unroll
    for (int p = 0; p < NPASS; ++p) {
        if (idx[p] >= 0) {
            const float4* __restrict__ rp =
                reinterpret_cast<const float4*>(emb_o + (size_t)idx[p] * DIM) + sub;
            float4 r[8];
            #pragma unroll
            for (int u = 0; u < 8; ++u) r[u] = rp[4 * u];
            float a0 = 0.f, a1 = 0.f, a2 = 0.f, a3 = 0.f;
            #pragma unroll
            for (int u = 0; u < 8; ++u) {
                a0 = fmaf(qv[u].x, r[u].x, a0);
                a1 = fmaf(qv[u].y, r[u].y, a1);
                a2 = fmaf(qv[u].z, r[u].z, a2);
                a3 = fmaf(qv[u].w, r[u].w, a3);
            }
            float pd = (a0 + a1) + (a2 + a3);
            pd += __shfl_xor(pd, 1, 64);
            pd += __shfl_xor(pd, 2, 64);
            const int j = gl + GPR * p;
            acc += log_sigmoid((j < CTX) ? pd : -pd);
        }
    }
    #pragma unroll
    for (int off = 32; off > 0; off >>= 1)
        acc += __shfl_xor(acc, off, 64);
    if ((threadIdx.x & 63) == 0) wsum[gtid >> 6] = acc;
}

__global__ __launch_bounds__(256) void sgns_reduce_fb(
    const float* __restrict__ wsum, float* __restrict__ out)
{
    __shared__ float s[4];
    const int tid = threadIdx.x;
    float acc = 0.0f;
    #pragma unroll
    for (int k = 0; k < 8; ++k) {
        const float4 v = reinterpret_cast<const float4*>(wsum)[tid + 256 * k];
        acc += (v.x + v.y) + (v.z + v.w);
    }
    #pragma unroll
    for (int off = 32; off > 0; off >>= 1)
        acc += __shfl_xor(acc, off, 64);
    if ((tid & 63) == 0) s[tid >> 6] = acc;
    __syncthreads();
    if (tid == 0)
        out[0] = -0.25f * (s[0] + s[1] + s[2] + s[3]) / (float)(BATCH * CTX);
}

extern "C" void kernel_launch(void* const* d_in, const int* in_sizes, int n_in,
                              void* d_out, int out_size, void* d_ws, size_t ws_size,
                              hipStream_t stream) {
    const float* emb_i  = (const float*)d_in[0];
    const float* emb_o  = (const float*)d_in[1];
    const int*   iword  = (const int*)d_in[2];
    const int*   owords = (const int*)d_in[3];
    const int*   nwords = (const int*)d_in[4];
    float* out = (float*)d_out;
    char*  ws  = (char*)d_ws;

    if (ws_size >= WS_NEED) {
        _Float16* embo_h = (_Float16*)(ws + WS_EMBO);
        _Float16* ivec_h = (_Float16*)(ws + WS_IVEC);
        float* partials  = (float*)(ws + WS_PART);

        conv_embo<<<V * DIM / (256 * 8), 256, 0, stream>>>(emb_o, embo_h);
        conv_ivec<<<BATCH * 16 / 256, 256, 0, stream>>>(emb_i, iword, ivec_h);
        sgns_neg<<<NNEGBLK, 256, 0, stream>>>(embo_h, ivec_h, nwords, partials);
        sgns_pos<<<NPOSBLK, 256, 0, stream>>>(embo_h, ivec_h, owords, partials);
        sgns_reduce<<<1, 256, 0, stream>>>(partials, out);
    } else {
        float* wsum = (float*)ws;
        sgns_partial_fb<<<BATCH * GPR * 4 / 256, 256, 0, stream>>>(
            emb_i, emb_o, iword, owords, nwords, wsum);
        sgns_reduce_fb<<<1, 256, 0, stream>>>(wsum, out);
    }
}

// Round 13
// 37.862 us; speedup vs baseline: 1.3808x; 1.3808x over previous
//
#include <hip/hip_runtime.h>

#define BATCH 4096
#define CTX 10
#define NEG 20
#define DIM 128
#define NPOS (BATCH * CTX)            // 40960
#define NNEG (BATCH * CTX * NEG)      // 819200
#define WSTRIP 512                    // negative occurrences per wave-task
#define NWSTRIP (NNEG / WSTRIP)       // 1600
#define NWTASK (NWSTRIP * 8)          // 12800 neg wave partials
#define WPB 2                         // wave-tasks per block (128-thread blocks)
#define NNEGBLK (NWTASK / WPB)        // 6400 neg blocks
#define NPOSBLK (NPOS / 32)           // 1280 pos blocks (32 items/block)
#define NBLK (NNEGBLK + NPOSBLK)      // 7680
#define NPART (NWTASK + NPOSBLK * 2)  // 15360 wave partials
#define IVSTR 136                     // padded LDS ivec row stride (floats)

__device__ __forceinline__ float log_sigmoid(float x) {
    return fminf(x, 0.0f) - __logf(1.0f + __expf(-fabsf(x)));
}

// Fused kernel, 128-thread blocks (2 waves) so 16 blocks/CU x 2 = 32 waves/CU.
// Neg blocks: wave-task = 512 consecutive nwords occ x slice (blockIdx&7 ->
// one XCD; emb_o slice L2-resident, proven R8). Barrier-free: wave-private
// LDS ivec rows + queue; 8-lane groups, 2-deep pipeline (R10 structure).
__global__ __launch_bounds__(128) void sgns_fused(
    const float* __restrict__ emb_i, const float* __restrict__ emb_o,
    const int* __restrict__ iword, const int* __restrict__ owords,
    const int* __restrict__ nwords, float* __restrict__ partials)
{
    __shared__ float s_ivec[WPB][4 * IVSTR];
    __shared__ int   wq[WPB][WSTRIP];

    const int tid  = threadIdx.x;
    const int wave = tid >> 6;
    const int lane = tid & 63;
    const int blk  = blockIdx.x;

    if (blk < NNEGBLK) {
        // ---------------- negatives ----------------
        const int slice = blk & 7;
        const int ws    = (blk >> 3) * WPB + wave;      // [0, 1600)
        const int wbase = ws * WSTRIP;
        const int b_lo  = wbase / 200;

        // stage this wave's <=4 ivec rows (wave-private)
        float* __restrict__ siv = s_ivec[wave];
        #pragma unroll
        for (int t = lane; t < 128; t += 64) {
            const int r = t >> 5, f = t & 31;
            const int iw = iword[min(b_lo + r, BATCH - 1)];
            *reinterpret_cast<float4*>(&siv[r * IVSTR + 4 * f]) =
                *reinterpret_cast<const float4*>(emb_i + (size_t)iw * DIM + 4 * f);
        }

        // ballot-compact 512 occurrences into the wave-private queue
        int* __restrict__ q = wq[wave];
        const unsigned long long lt = (1ull << lane) - 1;
        int qn = 0;
        #pragma unroll
        for (int h = 0; h < 8; ++h) {
            const int j  = wbase + h * 64 + lane;       // coalesced
            const int w  = nwords[j];
            const int bl = j / 200 - b_lo;              // 0..3
            const bool keep = ((w & 7) == slice);
            const unsigned long long m = __ballot(keep);
            if (keep) q[qn + __popcll(m & lt)] = (w << 2) | bl;
            qn += __popcll(m);                          // wave-uniform
        }

        // 8 groups x 8 lanes; 2-deep software pipeline
        const int g = lane >> 3, sub = lane & 7;
        float acc = 0.0f;
        float4 cur[4], nxt[4];
        int i = g;
        if (i < qn) {
            const float4* __restrict__ rp =
                reinterpret_cast<const float4*>(emb_o + (size_t)(q[i] >> 2) * DIM) + sub;
            #pragma unroll
            for (int u = 0; u < 4; ++u) cur[u] = rp[8 * u];
        }
        for (; i < qn; i += 8) {
            const int pk = q[i];
            const int i2 = i + 8;
            if (i2 < qn) {
                const float4* __restrict__ rp =
                    reinterpret_cast<const float4*>(emb_o + (size_t)(q[i2] >> 2) * DIM) + sub;
                #pragma unroll
                for (int u = 0; u < 4; ++u) nxt[u] = rp[8 * u];
            }
            __builtin_amdgcn_sched_barrier(0);   // prefetch issues before compute

            const float* __restrict__ qp = &siv[(pk & 3) * IVSTR + 4 * sub];
            float a0 = 0.f, a1 = 0.f, a2 = 0.f, a3 = 0.f;
            #pragma unroll
            for (int u = 0; u < 4; ++u) {
                const float4 qv = *reinterpret_cast<const float4*>(qp + 32 * u);
                a0 = fmaf(qv.x, cur[u].x, a0);
                a1 = fmaf(qv.y, cur[u].y, a1);
                a2 = fmaf(qv.z, cur[u].z, a2);
                a3 = fmaf(qv.w, cur[u].w, a3);
            }
            float pd = (a0 + a1) + (a2 + a3);
            pd += __shfl_xor(pd, 1, 64);
            pd += __shfl_xor(pd, 2, 64);
            pd += __shfl_xor(pd, 4, 64);
            acc += log_sigmoid(-pd);             // counted 8x; scaled at write

            #pragma unroll
            for (int u = 0; u < 4; ++u) cur[u] = nxt[u];
        }

        #pragma unroll
        for (int off = 32; off > 0; off >>= 1)
            acc += __shfl_xor(acc, off, 64);
        if (lane == 0)
            partials[blk * WPB + wave] = 0.125f * acc;
    } else {
        // ---------------- positives (4.7%) ----------------
        const int pblk = blk - NNEGBLK;
        const int item = pblk * 32 + (tid >> 2);        // < NPOS (exact)
        const int sub  = tid & 3;
        const int b    = item / 10;
        const int w    = owords[item];                  // 4 lanes same addr
        const int iw   = iword[b];

        const float4* __restrict__ qp =
            reinterpret_cast<const float4*>(emb_i + (size_t)iw * DIM) + sub;
        const float4* __restrict__ rp =
            reinterpret_cast<const float4*>(emb_o + (size_t)w * DIM) + sub;
        float4 r[8], qv[8];
        #pragma unroll
        for (int u = 0; u < 8; ++u) { r[u] = rp[4 * u]; qv[u] = qp[4 * u]; }
        float a0 = 0.f, a1 = 0.f, a2 = 0.f, a3 = 0.f;
        #pragma unroll
        for (int u = 0; u < 8; ++u) {
            a0 = fmaf(qv[u].x, r[u].x, a0);
            a1 = fmaf(qv[u].y, r[u].y, a1);
            a2 = fmaf(qv[u].z, r[u].z, a2);
            a3 = fmaf(qv[u].w, r[u].w, a3);
        }
        float pd = (a0 + a1) + (a2 + a3);
        pd += __shfl_xor(pd, 1, 64);
        pd += __shfl_xor(pd, 2, 64);
        float acc = log_sigmoid(pd);

        #pragma unroll
        for (int off = 32; off > 0; off >>= 1)
            acc += __shfl_xor(acc, off, 64);
        if (lane == 0)
            partials[NWTASK + pblk * 2 + wave] = 0.25f * acc;
    }
}

__global__ __launch_bounds__(256) void sgns_reduce(
    const float* __restrict__ partials, float* __restrict__ out)
{
    __shared__ float s[4];
    const int tid = threadIdx.x;
    // 15360 floats = 256 threads x 15 float4, coalesced
    float acc = 0.0f;
    #pragma unroll
    for (int k = 0; k < 15; ++k) {
        const float4 v = reinterpret_cast<const float4*>(partials)[tid + 256 * k];
        acc += (v.x + v.y) + (v.z + v.w);
    }
    #pragma unroll
    for (int off = 32; off > 0; off >>= 1)
        acc += __shfl_xor(acc, off, 64);
    if ((tid & 63) == 0) s[tid >> 6] = acc;
    __syncthreads();
    if (tid == 0)
        out[0] = -(s[0] + s[1] + s[2] + s[3]) / (float)(BATCH * CTX);
}

// ---------------- fallback (R6) if ws too small ----------------
#define NWORDS (CTX + CTX * NEG)
#define GPR 32
#define NPASS 7

__global__ __launch_bounds__(256) void sgns_partial_fb(
    const float* __restrict__ emb_i, const float* __restrict__ emb_o,
    const int* __restrict__ iword, const int* __restrict__ owords,
    const int* __restrict__ nwords, float* __restrict__ wsum)
{
    const int gtid = blockIdx.x * 256 + threadIdx.x;
    const int G = gtid >> 2, sub = gtid & 3;
    const int b = G >> 5, gl = G & 31;
    const int iw = iword[b];
    const float4* __restrict__ qp =
        reinterpret_cast<const float4*>(emb_i + (size_t)iw * DIM) + sub;
    float4 qv[8];
    #pragma unroll
    for (int u = 0; u < 8; ++u) qv[u] = qp[4 * u];
    int idx[NPASS];
    #pragma unroll
    for (int p = 0; p < NPASS; ++p) {
        const int j = gl + GPR * p;
        idx[p] = (j >= NWORDS) ? -1
               : (j < CTX)     ? owords[b * CTX + j]
                               : nwords[b * (CTX * NEG) + (j - CTX)];
    }
    float acc = 0.0f;
    #pragma unroll
    for (int p = 0; p < NPASS; ++p) {
        if (idx[p] >= 0) {
            const float4* __restrict__ rp =
                reinterpret_cast<const float4*>(emb_o + (size_t)idx[p] * DIM) + sub;
            float4 r[8];
            #pragma unroll
            for (int u = 0; u < 8; ++u) r[u] = rp[4 * u];
            float a0 = 0.f, a1 = 0.f, a2 = 0.f, a3 = 0.f;
            #pragma unroll
            for (int u = 0; u < 8; ++u) {
                a0 = fmaf(qv[u].x, r[u].x, a0);
                a1 = fmaf(qv[u].y, r[u].y, a1);
                a2 = fmaf(qv[u].z, r[u].z, a2);
                a3 = fmaf(qv[u].w, r[u].w, a3);
            }
            float pd = (a0 + a1) + (a2 + a3);
            pd += __shfl_xor(pd, 1, 64);
            pd += __shfl_xor(pd, 2, 64);
            const int j = gl + GPR * p;
            acc += log_sigmoid((j < CTX) ? pd : -pd);
        }
    }
    #pragma unroll
    for (int off = 32; off > 0; off >>= 1)
        acc += __shfl_xor(acc, off, 64);
    if ((threadIdx.x & 63) == 0) wsum[gtid >> 6] = acc;
}

__global__ __launch_bounds__(256) void sgns_reduce_fb(
    const float* __restrict__ wsum, float* __restrict__ out)
{
    __shared__ float s[4];
    const int tid = threadIdx.x;
    float acc = 0.0f;
    #pragma unroll
    for (int k = 0; k < 8; ++k) {
        const float4 v = reinterpret_cast<const float4*>(wsum)[tid + 256 * k];
        acc += (v.x + v.y) + (v.z + v.w);
    }
    #pragma unroll
    for (int off = 32; off > 0; off >>= 1)
        acc += __shfl_xor(acc, off, 64);
    if ((tid & 63) == 0) s[tid >> 6] = acc;
    __syncthreads();
    if (tid == 0)
        out[0] = -0.25f * (s[0] + s[1] + s[2] + s[3]) / (float)(BATCH * CTX);
}

extern "C" void kernel_launch(void* const* d_in, const int* in_sizes, int n_in,
                              void* d_out, int out_size, void* d_ws, size_t ws_size,
                              hipStream_t stream) {
    const float* emb_i  = (const float*)d_in[0];
    const float* emb_o  = (const float*)d_in[1];
    const int*   iword  = (const int*)d_in[2];
    const int*   owords = (const int*)d_in[3];
    const int*   nwords = (const int*)d_in[4];
    float* out = (float*)d_out;

    if (ws_size >= (size_t)(NPART * 4)) {
        float* partials = (float*)d_ws;
        sgns_fused<<<NBLK, 128, 0, stream>>>(emb_i, emb_o, iword, owords,
                                             nwords, partials);
        sgns_reduce<<<1, 256, 0, stream>>>(partials, out);
    } else {
        float* wsum = (float*)d_ws;
        sgns_partial_fb<<<BATCH * GPR * 4 / 256, 256, 0, stream>>>(
            emb_i, emb_o, iword, owords, nwords, wsum);
        sgns_reduce_fb<<<1, 256, 0, stream>>>(wsum, out);
    }
}

// Round 14
// 35.520 us; speedup vs baseline: 1.4718x; 1.0659x over previous
//
#include <hip/hip_runtime.h>

#define BATCH 4096
#define CTX 10
#define NEG 20
#define DIM 128
#define V 50000
#define NPOS (BATCH * CTX)            // 40960
#define NNEG (BATCH * CTX * NEG)      // 819200
#define WSTRIP 512                    // negative occurrences per wave-task
#define NWSTRIP (NNEG / WSTRIP)       // 1600
#define NWTASK (NWSTRIP * 8)          // 12800 neg wave partials
#define WPB 2                         // wave-tasks per block (128-thread blocks)
#define NNEGBLK (NWTASK / WPB)        // 6400 neg blocks
#define NPOSBLK (NPOS / 32)           // 1280 pos blocks (32 items each)
#define NBLK (NNEGBLK + NPOSBLK)      // 7680
#define NPART (NWTASK + NPOSBLK * 2)  // 15360 wave partials
#define IVSTR 136                     // LDS ivec row stride in halves (272B, 16B-aligned)

// ---- workspace layout (bytes); ws ~268MB observed ----
#define WS_EMBO 0
#define WS_EMBO_SZ ((size_t)V * DIM * 2)              // 12.8 MB f16
#define WS_IVEC (WS_EMBO + WS_EMBO_SZ)
#define WS_IVEC_SZ ((size_t)BATCH * DIM * 2)          // 1 MB f16
#define WS_PART (WS_IVEC + WS_IVEC_SZ)
#define WS_NEED (WS_PART + (size_t)NPART * 4)

typedef _Float16 half2v __attribute__((ext_vector_type(2)));
// EXACTLY 16 bytes: one uint4 <-> 4 half2 <-> 8 f16
union U16 { uint4 u; half2v h[4]; _Float16 f[8]; };

__device__ __forceinline__ float log_sigmoid(float x) {
    return fminf(x, 0.0f) - __logf(1.0f + __expf(-fabsf(x)));
}

// dot of one 16B chunk each side (8 f16 pairs), f32 accumulate
__device__ __forceinline__ float dot16(const uint4& a, const uint4& b, float acc) {
    U16 ua, ub; ua.u = a; ub.u = b;
#if __has_builtin(__builtin_amdgcn_fdot2)
    #pragma unroll
    for (int j = 0; j < 4; ++j)
        acc = __builtin_amdgcn_fdot2(ua.h[j], ub.h[j], acc, false);
#else
    #pragma unroll
    for (int j = 0; j < 8; ++j)
        acc = fmaf((float)ua.f[j], (float)ub.f[j], acc);
#endif
    return acc;
}

// emb_o f32 -> f16 (streaming; 3125 blocks x 8 elems/thread)
__global__ __launch_bounds__(256) void conv_embo(
    const float* __restrict__ emb_o, _Float16* __restrict__ embo_h)
{
    const size_t gid = (size_t)blockIdx.x * 256 + threadIdx.x;
    const float4 a = reinterpret_cast<const float4*>(emb_o)[2 * gid];
    const float4 b = reinterpret_cast<const float4*>(emb_o)[2 * gid + 1];
    U16 o;
    o.f[0]=(_Float16)a.x; o.f[1]=(_Float16)a.y; o.f[2]=(_Float16)a.z; o.f[3]=(_Float16)a.w;
    o.f[4]=(_Float16)b.x; o.f[5]=(_Float16)b.y; o.f[6]=(_Float16)b.z; o.f[7]=(_Float16)b.w;
    reinterpret_cast<uint4*>(embo_h)[gid] = o.u;
}

// gather+convert the 4096 used ivecs -> dense f16 table (256 blocks)
__global__ __launch_bounds__(256) void conv_ivec(
    const float* __restrict__ emb_i, const int* __restrict__ iword,
    _Float16* __restrict__ ivec_h)
{
    const int gid = blockIdx.x * 256 + threadIdx.x;   // 16 threads per row
    const int row = gid >> 4, f = gid & 15;
    const int iw  = iword[row];
    const float4 a = reinterpret_cast<const float4*>(emb_i)[(size_t)iw * 32 + 2 * f];
    const float4 b = reinterpret_cast<const float4*>(emb_i)[(size_t)iw * 32 + 2 * f + 1];
    U16 o;
    o.f[0]=(_Float16)a.x; o.f[1]=(_Float16)a.y; o.f[2]=(_Float16)a.z; o.f[3]=(_Float16)a.w;
    o.f[4]=(_Float16)b.x; o.f[5]=(_Float16)b.y; o.f[6]=(_Float16)b.z; o.f[7]=(_Float16)b.w;
    reinterpret_cast<uint4*>(ivec_h)[(size_t)row * 16 + f] = o.u;
}

// Fused f16 kernel, 128-thr blocks (16 blocks/CU x 2 waves = 32 waves/CU, R13).
// Neg: wave-task = 512 consecutive nwords occ x slice (blockIdx&7 -> one XCD;
// emb_o slice L2-resident). Barrier-free, wave-private LDS. 4-lane groups:
// 16 items/round, 4 rounds/task, 2-deep pipeline. Row = 256B = 4 lines/item.
__global__ __launch_bounds__(128) void sgns_fused(
    const _Float16* __restrict__ embo_h, const _Float16* __restrict__ ivec_h,
    const int* __restrict__ owords, const int* __restrict__ nwords,
    float* __restrict__ partials)
{
    __shared__ _Float16 s_ivec[WPB][4 * IVSTR];
    __shared__ int      wq[WPB][WSTRIP];

    const int tid  = threadIdx.x;
    const int wave = tid >> 6;
    const int lane = tid & 63;
    const int blk  = blockIdx.x;

    if (blk < NNEGBLK) {
        // ---------------- negatives ----------------
        const int slice = blk & 7;
        const int ws    = (blk >> 3) * WPB + wave;      // [0, 1600)
        const int wbase = ws * WSTRIP;
        const int b_lo  = wbase / 200;

        // stage this wave's <=4 ivec rows (64 x 16B chunks, wave-private)
        _Float16* __restrict__ siv = s_ivec[wave];
        {
            const int r = lane >> 4, f = lane & 15;
            const int b = min(b_lo + r, BATCH - 1);
            const uint4 v = reinterpret_cast<const uint4*>(ivec_h)[(size_t)b * 16 + f];
            *reinterpret_cast<uint4*>(&siv[r * IVSTR + f * 8]) = v;
        }

        // ballot-compact 512 occurrences into the wave-private queue
        int* __restrict__ q = wq[wave];
        const unsigned long long lt = (1ull << lane) - 1;
        int qn = 0;
        #pragma unroll
        for (int h = 0; h < 8; ++h) {
            const int j  = wbase + h * 64 + lane;       // coalesced
            const int w  = nwords[j];
            const int bl = j / 200 - b_lo;              // 0..3
            const bool keep = ((w & 7) == slice);
            const unsigned long long m = __ballot(keep);
            if (keep) q[qn + __popcll(m & lt)] = (w << 2) | bl;
            qn += __popcll(m);                          // wave-uniform
        }

        // 16 groups x 4 lanes; 2-deep software pipeline; 4x16B per lane
        const int g = lane >> 2, sub = lane & 3;
        float acc = 0.0f;
        uint4 cur[4] = {}, nxt[4] = {};
        int i = g;
        if (i < qn) {
            const uint4* __restrict__ rp =
                reinterpret_cast<const uint4*>(embo_h + (size_t)(q[i] >> 2) * DIM);
            #pragma unroll
            for (int u = 0; u < 4; ++u) cur[u] = rp[sub + 4 * u];
        }
        for (; i < qn; i += 16) {
            const int pk = q[i];
            const int i2 = i + 16;
            if (i2 < qn) {
                const uint4* __restrict__ rp =
                    reinterpret_cast<const uint4*>(embo_h + (size_t)(q[i2] >> 2) * DIM);
                #pragma unroll
                for (int u = 0; u < 4; ++u) nxt[u] = rp[sub + 4 * u];
            }
            __builtin_amdgcn_sched_barrier(0);   // prefetch issues before compute

            const _Float16* __restrict__ qp = &siv[(pk & 3) * IVSTR + sub * 8];
            float pd = 0.0f;
            #pragma unroll
            for (int u = 0; u < 4; ++u) {
                const uint4 qv = *reinterpret_cast<const uint4*>(qp + 32 * u);
                pd = dot16(cur[u], qv, pd);
            }
            pd += __shfl_xor(pd, 1, 64);
            pd += __shfl_xor(pd, 2, 64);
            acc += log_sigmoid(-pd);             // counted 4x; scaled at write

            #pragma unroll
            for (int u = 0; u < 4; ++u) cur[u] = nxt[u];
        }

        #pragma unroll
        for (int off = 32; off > 0; off >>= 1)
            acc += __shfl_xor(acc, off, 64);
        if (lane == 0)
            partials[blk * WPB + wave] = 0.25f * acc;
    } else {
        // ---------------- positives (4.7%) ----------------
        const int pblk = blk - NNEGBLK;
        const int item = pblk * 32 + (tid >> 2);        // < NPOS (exact)
        const int sub  = tid & 3;
        const int b    = item / 10;
        const int w    = owords[item];                  // 4 lanes same addr

        const uint4* __restrict__ rp =
            reinterpret_cast<const uint4*>(embo_h + (size_t)w * DIM);
        const uint4* __restrict__ qp =
            reinterpret_cast<const uint4*>(ivec_h + (size_t)b * DIM);
        float pd = 0.0f;
        #pragma unroll
        for (int u = 0; u < 4; ++u)
            pd = dot16(rp[sub + 4 * u], qp[sub + 4 * u], pd);
        pd += __shfl_xor(pd, 1, 64);
        pd += __shfl_xor(pd, 2, 64);
        float acc = log_sigmoid(pd);

        #pragma unroll
        for (int off = 32; off > 0; off >>= 1)
            acc += __shfl_xor(acc, off, 64);
        if (lane == 0)
            partials[NWTASK + pblk * 2 + wave] = 0.25f * acc;
    }
}

__global__ __launch_bounds__(256) void sgns_reduce(
    const float* __restrict__ partials, float* __restrict__ out)
{
    __shared__ float s[4];
    const int tid = threadIdx.x;
    // 15360 floats = 256 threads x 15 float4, coalesced
    float acc = 0.0f;
    #pragma unroll
    for (int k = 0; k < 15; ++k) {
        const float4 v = reinterpret_cast<const float4*>(partials)[tid + 256 * k];
        acc += (v.x + v.y) + (v.z + v.w);
    }
    #pragma unroll
    for (int off = 32; off > 0; off >>= 1)
        acc += __shfl_xor(acc, off, 64);
    if ((tid & 63) == 0) s[tid >> 6] = acc;
    __syncthreads();
    if (tid == 0)
        out[0] = -(s[0] + s[1] + s[2] + s[3]) / (float)(BATCH * CTX);
}

// ---------------- fallback (R6, f32) if ws too small ----------------
#define NWORDS (CTX + CTX * NEG)
#define GPR 32
#define NPASS 7

__global__ __launch_bounds__(256) void sgns_partial_fb(
    const float* __restrict__ emb_i, const float* __restrict__ emb_o,
    const int* __restrict__ iword, const int* __restrict__ owords,
    const int* __restrict__ nwords, float* __restrict__ wsum)
{
    const int gtid = blockIdx.x * 256 + threadIdx.x;
    const int G = gtid >> 2, sub = gtid & 3;
    const int b = G >> 5, gl = G & 31;
    const int iw = iword[b];
    const float4* __restrict__ qp =
        reinterpret_cast<const float4*>(emb_i + (size_t)iw * DIM) + sub;
    float4 qv[8];
    #pragma unroll
    for (int u = 0; u < 8; ++u) qv[u] = qp[4 * u];
    int idx[NPASS];
    #pragma unroll
    for (int p = 0; p < NPASS; ++p) {
        const int j = gl + GPR * p;
        idx[p] = (j >= NWORDS) ? -1
               : (j < CTX)     ? owords[b * CTX + j]
                               : nwords[b * (CTX * NEG) + (j - CTX)];
    }
    float acc = 0.0f;
    #pragma unroll
    for (int p = 0; p < NPASS; ++p) {
        if (idx[p] >= 0) {
            const float4* __restrict__ rp =
                reinterpret_cast<const float4*>(emb_o + (size_t)idx[p] * DIM) + sub;
            float4 r[8];
            #pragma unroll
            for (int u = 0; u < 8; ++u) r[u] = rp[4 * u];
            float a0 = 0.f, a1 = 0.f, a2 = 0.f, a3 = 0.f;
            #pragma unroll
            for (int u = 0; u < 8; ++u) {
                a0 = fmaf(qv[u].x, r[u].x, a0);
                a1 = fmaf(qv[u].y, r[u].y, a1);
                a2 = fmaf(qv[u].z, r[u].z, a2);
                a3 = fmaf(qv[u].w, r[u].w, a3);
            }
            float pd = (a0 + a1) + (a2 + a3);
            pd += __shfl_xor(pd, 1, 64);
            pd += __shfl_xor(pd, 2, 64);
            const int j = gl + GPR * p;
            acc += log_sigmoid((j < CTX) ? pd : -pd);
        }
    }
    #pragma unroll
    for (int off = 32; off > 0; off >>= 1)
        acc += __shfl_xor(acc, off, 64);
    if ((threadIdx.x & 63) == 0) wsum[gtid >> 6] = acc;
}

__global__ __launch_bounds__(256) void sgns_reduce_fb(
    const float* __restrict__ wsum, float* __restrict__ out)
{
    __shared__ float s[4];
    const int tid = threadIdx.x;
    float acc = 0.0f;
    #pragma unroll
    for (int k = 0; k < 8; ++k) {
        const float4 v = reinterpret_cast<const float4*>(wsum)[tid + 256 * k];
        acc += (v.x + v.y) + (v.z + v.w);
    }
    #pragma unroll
    for (int off = 32; off > 0; off >>= 1)
        acc += __shfl_xor(acc, off, 64);
    if ((tid & 63) == 0) s[tid >> 6] = acc;
    __syncthreads();
    if (tid == 0)
        out[0] = -0.25f * (s[0] + s[1] + s[2] + s[3]) / (float)(BATCH * CTX);
}

extern "C" void kernel_launch(void* const* d_in, const int* in_sizes, int n_in,
                              void* d_out, int out_size, void* d_ws, size_t ws_size,
                              hipStream_t stream) {
    const float* emb_i  = (const float*)d_in[0];
    const float* emb_o  = (const float*)d_in[1];
    const int*   iword  = (const int*)d_in[2];
    const int*   owords = (const int*)d_in[3];
    const int*   nwords = (const int*)d_in[4];
    float* out = (float*)d_out;
    char*  ws  = (char*)d_ws;

    if (ws_size >= WS_NEED) {
        _Float16* embo_h = (_Float16*)(ws + WS_EMBO);
        _Float16* ivec_h = (_Float16*)(ws + WS_IVEC);
        float* partials  = (float*)(ws + WS_PART);

        conv_embo<<<V * DIM / (256 * 8), 256, 0, stream>>>(emb_o, embo_h);
        conv_ivec<<<BATCH * 16 / 256, 256, 0, stream>>>(emb_i, iword, ivec_h);
        sgns_fused<<<NBLK, 128, 0, stream>>>(embo_h, ivec_h, owords, nwords, partials);
        sgns_reduce<<<1, 256, 0, stream>>>(partials, out);
    } else {
        float* wsum = (float*)ws;
        sgns_partial_fb<<<BATCH * GPR * 4 / 256, 256, 0, stream>>>(
            emb_i, emb_o, iword, owords, nwords, wsum);
        sgns_reduce_fb<<<1, 256, 0, stream>>>(wsum, out);
    }
}